// Round 9
// baseline (341.257 us; speedup 1.0000x reference)
//
#include <hip/hip_runtime.h>
#include <math.h>

#define NF 15552      // B*T
#define NJ 17
#define NC 128
#define JC 2176       // NJ*NC
#define TT 243        // frames per batch
#define FPB 12        // frames per fused block; grid = 1296
#define GRID_FUSED (NF/FPB)

constexpr int cA[15] = {0,1,2,0,4,5,0,7,8,0,10,11,0,13,14};
constexpr int cB[15] = {1,2,3,4,5,6,7,8,9,10,11,12,13,14,15};
constexpr int aJ[4] = {11,14,5,8};
constexpr int aP[4] = {10,13,4,7};
constexpr int aCc[4] = {12,15,6,9};

__device__ const int d_cA16[16] = {0,1,2,0,4,5,0,7,8,0,10,11,0,13,14,0};
__device__ const int d_cB16[16] = {1,2,3,4,5,6,7,8,9,10,11,12,13,14,15,0};

typedef __bf16 bf16x8 __attribute__((ext_vector_type(8)));
typedef float f32x4 __attribute__((ext_vector_type(4)));
typedef unsigned short u16x8 __attribute__((ext_vector_type(8)));

// ws layout (bytes): [0) mean_acc 64*JC f32 | [557056) wb frags 65536 | [622592) wa frags 16384
#define WSO_WB 557056
#define WSO_WA 622592

__device__ __forceinline__ float gelu_exact(float x){
  return 0.5f * x * (1.0f + erff(x * 0.7071067811865476f));
}
__device__ __forceinline__ float gelu_fast(float x){
  const float s2 = x * x;
  const float q  = fmaf(s2, -0.1029437f, -2.3021183f);
  const float e  = __builtin_amdgcn_exp2f(q * x);
  return x * __builtin_amdgcn_rcpf(1.0f + e);
}
__device__ __forceinline__ unsigned short bfc(float x){
  return __builtin_bit_cast(unsigned short, (__bf16)x);
}

// ---------------- prep: weights -> bf16 MFMA-fragment layout in ws ----------------
// wb unit u (0..4095): lane=u&63, ks=(u>>6)&7, nf=(u>>9)&1, widx=u>>10
//   col = widx*32+nf*16+(lane&15); elem e = bw1[(ks*32+(lane>>4)*8+e)*128 + col]
// wa unit v (0..1023): lane=v&63, nf=(v>>6)&3, kt=v>>8
//   col = nf*16+(lane&15);        elem e = aw1[(kt*32+(lane>>4)*8+e)*64 + col]
__global__ __launch_bounds__(256) void k_prep(const float* __restrict__ bw1,
                                              const float* __restrict__ aw1,
                                              unsigned short* __restrict__ ws_wb,
                                              unsigned short* __restrict__ ws_wa)
{
  const int u = blockIdx.x*256 + threadIdx.x;
  if (u < 4096){
    const int lane = u & 63, ks = (u>>6)&7, nf = (u>>9)&1, widx = u>>10;
    const int c = lane & 15, g = lane >> 4;
    const int col = widx*32 + nf*16 + c;
    u16x8 t;
    #pragma unroll
    for (int e = 0; e < 8; ++e) t[e] = bfc(bw1[(ks*32 + g*8 + e)*128 + col]);
    *(u16x8*)&ws_wb[u*8] = t;
  } else if (u < 4096 + 1024){
    const int v = u - 4096;
    const int lane = v & 63, nf = (v>>6)&3, kt = v>>8;
    const int c = lane & 15, g = lane >> 4;
    const int col = nf*16 + c;
    u16x8 t;
    #pragma unroll
    for (int e = 0; e < 8; ++e) t[e] = bfc(aw1[(kt*32 + g*8 + e)*64 + col]);
    *(u16x8*)&ws_wa[v*8] = t;
  }
}

// ---------------- geometry + zeroing (LDS-staged pose reads) ----------------
__global__ __launch_bounds__(256) void k_geom(const float* __restrict__ pose,
                                              float* __restrict__ out_aa,
                                              float* __restrict__ out_abl,
                                              float* __restrict__ out_pbl,
                                              float* __restrict__ mean_acc)
{
  __shared__ float sp[256*51];
  const int tid = threadIdx.x;
  const int fbase = blockIdx.x * 256;
  const int nfr = min(256, NF - fbase);

  for (int u = tid; u < nfr*51; u += 256) sp[u] = pose[(long)fbase*51 + u];
  for (long i = (long)blockIdx.x*256 + tid; i < (long)NF*15; i += (long)gridDim.x*256)
    out_pbl[i] = 0.0f;
  for (long i = (long)blockIdx.x*256 + tid; i < 64L*JC; i += (long)gridDim.x*256)
    mean_acc[i] = 0.0f;
  __syncthreads();

  if (tid < nfr){
    const int f = fbase + tid;
    const float* p = sp + tid*51;
    float px[NJ], py[NJ], pz[NJ];
    #pragma unroll
    for (int j = 0; j < NJ; ++j){ px[j] = p[3*j]; py[j] = p[3*j+1]; pz[j] = p[3*j+2]; }

    #pragma unroll
    for (int i = 0; i < 15; ++i){
      const int a = cA[i], b = cB[i];
      const float dx = px[b]-px[a], dy = py[b]-py[a], dz = pz[b]-pz[a];
      out_abl[(long)f*15 + i] = sqrtf(dx*dx + dy*dy + dz*dz);
    }

    float ang[NJ];
    #pragma unroll
    for (int j = 0; j < NJ; ++j) ang[j] = 0.0f;
    #pragma unroll
    for (int i = 0; i < 4; ++i){
      const int jj = aJ[i], pp = aP[i], cc = aCc[i];
      float v1x = px[jj]-px[pp], v1y = py[jj]-py[pp], v1z = pz[jj]-pz[pp];
      float v2x = px[cc]-px[jj], v2y = py[cc]-py[jj], v2z = pz[cc]-pz[jj];
      const float n1 = sqrtf(v1x*v1x + v1y*v1y + v1z*v1z) + 1e-10f;
      const float n2 = sqrtf(v2x*v2x + v2y*v2y + v2z*v2z) + 1e-10f;
      v1x /= n1; v1y /= n1; v1z /= n1;
      v2x /= n2; v2y /= n2; v2z /= n2;
      float d = v1x*v2x + v1y*v2y + v1z*v2z;
      d = fminf(fmaxf(d, -1.0f + 1e-7f), 1.0f - 1e-7f);
      ang[jj] = acosf(d);
    }
    #pragma unroll
    for (int j = 0; j < NJ; ++j) out_aa[(long)f*NJ + j] = ang[j];
  }
}

// ---------------- fused streaming: angle(+mean) wave + 4 bone waves ----------------
// Zero LDS, zero barriers. A-fragments loaded global->reg->bf16.
__global__ __launch_bounds__(320) void k_fused(const float* __restrict__ feat,
    const float* __restrict__ ab1, const float* __restrict__ aw2,
    const float* __restrict__ ab2,
    const float* __restrict__ bb1, const float* __restrict__ bw2,
    const unsigned short* __restrict__ ws_wb,
    const unsigned short* __restrict__ ws_wa,
    float* __restrict__ out_pa, float* __restrict__ out_pbl,
    float* __restrict__ mean_acc)
{
  const int tid  = threadIdx.x;
  const int w    = tid >> 6;
  const int lane = tid & 63;
  const int g    = lane >> 4;
  const int c    = lane & 15;
  const long F0  = (long)blockIdx.x * FPB;

  if (w == 0){
    // ================= ANGLE + MEAN =================
    float ab1c[4], aw2c[4][3];
    #pragma unroll
    for (int nf = 0; nf < 4; ++nf){
      const int col = nf*16 + c;
      ab1c[nf] = ab1[col];
      #pragma unroll
      for (int m = 0; m < 3; ++m) aw2c[nf][m] = aw2[col*3 + m];
    }
    const float ab2c[3] = {ab2[0], ab2[1], ab2[2]};

    float macc[4][8];       // joint c, channels kt*32+g*8+e
    float macc16[8];        // j16 channels (c&3)*32+g*8+e (flushed from c<4)
    #pragma unroll
    for (int kt = 0; kt < 4; ++kt)
      #pragma unroll
      for (int e = 0; e < 8; ++e) macc[kt][e] = 0.0f;
    #pragma unroll
    for (int e = 0; e < 8; ++e) macc16[e] = 0.0f;

    const int b0 = (int)(F0 / TT);
    const long bsplit = (long)(b0 + 1) * TT;
    int curb = b0;

    auto flushMean = [&](int batch){
      float* ma = mean_acc + (long)batch*JC;
      #pragma unroll
      for (int kt = 0; kt < 4; ++kt)
        #pragma unroll
        for (int e = 0; e < 8; ++e){
          atomicAdd(&ma[c*128 + kt*32 + g*8 + e], macc[kt][e]);
          macc[kt][e] = 0.0f;
        }
      if (c < 4){
        #pragma unroll
        for (int e = 0; e < 8; ++e) atomicAdd(&ma[2048 + c*32 + g*8 + e], macc16[e]);
      }
      #pragma unroll
      for (int e = 0; e < 8; ++e) macc16[e] = 0.0f;
    };

    for (int f = 0; f < FPB; ++f){
      const long frame = F0 + f;
      if (frame == bsplit){ flushMean(b0); curb = b0 + 1; }
      const float* fb = feat + frame*JC;

      f32x4 accJ[4], accX[4];
      #pragma unroll
      for (int nf = 0; nf < 4; ++nf){ accJ[nf] = (f32x4)0.0f; accX[nf] = (f32x4)0.0f; }

      #pragma unroll
      for (int kt = 0; kt < 4; ++kt){
        // joint-tile A: row = c (joint), k = kt*32+g*8..+7
        const float* pj = fb + c*128 + kt*32 + g*8;
        const float4 a0 = *(const float4*)pj;
        const float4 a1 = *(const float4*)(pj + 4);
        macc[kt][0]+=a0.x; macc[kt][1]+=a0.y; macc[kt][2]+=a0.z; macc[kt][3]+=a0.w;
        macc[kt][4]+=a1.x; macc[kt][5]+=a1.y; macc[kt][6]+=a1.z; macc[kt][7]+=a1.w;
        u16x8 ta;
        ta[0]=bfc(a0.x); ta[1]=bfc(a0.y); ta[2]=bfc(a0.z); ta[3]=bfc(a0.w);
        ta[4]=bfc(a1.x); ta[5]=bfc(a1.y); ta[6]=bfc(a1.z); ta[7]=bfc(a1.w);
        const bf16x8 av = __builtin_bit_cast(bf16x8, ta);
        // j16 A: uniform over c -> every D row equals the j16 result
        const float* px = fb + 16*128 + kt*32 + g*8;
        const float4 x0 = *(const float4*)px;
        const float4 x1 = *(const float4*)(px + 4);
        if (kt == (c & 3)){
          macc16[0]+=x0.x; macc16[1]+=x0.y; macc16[2]+=x0.z; macc16[3]+=x0.w;
          macc16[4]+=x1.x; macc16[5]+=x1.y; macc16[6]+=x1.z; macc16[7]+=x1.w;
        }
        u16x8 tx;
        tx[0]=bfc(x0.x); tx[1]=bfc(x0.y); tx[2]=bfc(x0.z); tx[3]=bfc(x0.w);
        tx[4]=bfc(x1.x); tx[5]=bfc(x1.y); tx[6]=bfc(x1.z); tx[7]=bfc(x1.w);
        const bf16x8 avx = __builtin_bit_cast(bf16x8, tx);

        #pragma unroll
        for (int nf = 0; nf < 4; ++nf){
          const bf16x8 wf = __builtin_bit_cast(bf16x8,
              *(const u16x8*)&ws_wa[((kt*4 + nf)*64 + lane)*8]);
          accJ[nf] = __builtin_amdgcn_mfma_f32_16x16x32_bf16(av,  wf, accJ[nf], 0, 0, 0);
          accX[nf] = __builtin_amdgcn_mfma_f32_16x16x32_bf16(avx, wf, accX[nf], 0, 0, 0);
        }
      }

      // epilogue: joints 0-15
      float s[4][3];
      #pragma unroll
      for (int r = 0; r < 4; ++r){ s[r][0]=0.f; s[r][1]=0.f; s[r][2]=0.f; }
      float s16[3] = {0.f, 0.f, 0.f};
      #pragma unroll
      for (int nf = 0; nf < 4; ++nf){
        #pragma unroll
        for (int r = 0; r < 4; ++r){
          const float h = gelu_fast(accJ[nf][r] + ab1c[nf]);
          s[r][0] = fmaf(h, aw2c[nf][0], s[r][0]);
          s[r][1] = fmaf(h, aw2c[nf][1], s[r][1]);
          s[r][2] = fmaf(h, aw2c[nf][2], s[r][2]);
        }
        const float hx = gelu_fast(accX[nf][0] + ab1c[nf]);   // rows all equal
        s16[0] = fmaf(hx, aw2c[nf][0], s16[0]);
        s16[1] = fmaf(hx, aw2c[nf][1], s16[1]);
        s16[2] = fmaf(hx, aw2c[nf][2], s16[2]);
      }
      #pragma unroll
      for (int r = 0; r < 4; ++r)
        #pragma unroll
        for (int m = 0; m < 3; ++m){
          float v = s[r][m];
          v += __shfl_xor(v, 1);
          v += __shfl_xor(v, 2);
          v += __shfl_xor(v, 4);
          v += __shfl_xor(v, 8);
          s[r][m] = v;
        }
      #pragma unroll
      for (int m = 0; m < 3; ++m){
        float v = s16[m];
        v += __shfl_xor(v, 1);
        v += __shfl_xor(v, 2);
        v += __shfl_xor(v, 4);
        v += __shfl_xor(v, 8);
        s16[m] = v;
      }
      if (c == 0){
        #pragma unroll
        for (int r = 0; r < 4; ++r){
          const int joint = g*4 + r;
          #pragma unroll
          for (int m = 0; m < 3; ++m)
            out_pa[(frame*NJ + joint)*3 + m] = s[r][m] + ab2c[m];
        }
      }
      if (lane == 0){
        #pragma unroll
        for (int m = 0; m < 3; ++m)
          out_pa[(frame*NJ + 16)*3 + m] = s16[m] + ab2c[m];
      }
    }
    flushMean(curb);
  } else {
    // ================= BONE (4 waves x 32 cols) =================
    const int widx = w - 1;
    bf16x8 wb[8][2];
    #pragma unroll
    for (int nf = 0; nf < 2; ++nf)
      #pragma unroll
      for (int ks = 0; ks < 8; ++ks)
        wb[ks][nf] = __builtin_bit_cast(bf16x8,
            *(const u16x8*)&ws_wb[((((widx*2 + nf)*8) + ks)*64 + lane)*8]);
    float bb1c[2], bw2c2[2];
    #pragma unroll
    for (int nf = 0; nf < 2; ++nf){
      const int col = widx*32 + nf*16 + c;
      bb1c[nf] = bb1[col];
      bw2c2[nf] = bw2[col];
    }
    const int jAo = d_cA16[c]*128, jBo = d_cB16[c]*128;

    for (int f = 0; f < FPB; ++f){
      const long frame = F0 + f;
      const float* fb = feat + frame*JC;
      f32x4 acc0 = (f32x4)0.0f, acc1 = (f32x4)0.0f;
      #pragma unroll
      for (int ks = 0; ks < 8; ++ks){
        const int ch = (ks & 3)*32 + g*8;
        const float* pa = fb + (ks < 4 ? jAo : jBo) + ch;
        const float4 a0 = *(const float4*)pa;
        const float4 a1 = *(const float4*)(pa + 4);
        u16x8 ta;
        ta[0]=bfc(a0.x); ta[1]=bfc(a0.y); ta[2]=bfc(a0.z); ta[3]=bfc(a0.w);
        ta[4]=bfc(a1.x); ta[5]=bfc(a1.y); ta[6]=bfc(a1.z); ta[7]=bfc(a1.w);
        const bf16x8 av = __builtin_bit_cast(bf16x8, ta);
        acc0 = __builtin_amdgcn_mfma_f32_16x16x32_bf16(av, wb[ks][0], acc0, 0, 0, 0);
        acc1 = __builtin_amdgcn_mfma_f32_16x16x32_bf16(av, wb[ks][1], acc1, 0, 0, 0);
      }
      float s[4];
      #pragma unroll
      for (int r = 0; r < 4; ++r)
        s[r] = gelu_fast(acc0[r] + bb1c[0]) * bw2c2[0]
             + gelu_fast(acc1[r] + bb1c[1]) * bw2c2[1];
      #pragma unroll
      for (int r = 0; r < 4; ++r){
        s[r] += __shfl_xor(s[r], 1);
        s[r] += __shfl_xor(s[r], 2);
        s[r] += __shfl_xor(s[r], 4);
        s[r] += __shfl_xor(s[r], 8);
      }
      if (c == 0){
        #pragma unroll
        for (int r = 0; r < 4; ++r){
          const int bone = g*4 + r;
          if (bone < 15) atomicAdd(&out_pbl[frame*15 + bone], s[r]);
        }
      }
    }
  }
}

// ---------------- pbl finalize: relu(partial + bb2) ----------------
__global__ __launch_bounds__(256) void k_pblfix(float* __restrict__ pbl,
                                                const float* __restrict__ bb2)
{
  const long i = (long)blockIdx.x*256 + threadIdx.x;
  if (i < (long)NF*15) pbl[i] = fmaxf(pbl[i] + bb2[0], 0.0f);
}

// ---------------- action classifier (reads per-batch sums) ----------------
__global__ __launch_bounds__(256) void k_action(const float* __restrict__ sum_src,
    const float* __restrict__ cw1, const float* __restrict__ cb1,
    const float* __restrict__ cw2, const float* __restrict__ cb2,
    float* __restrict__ out_lg)
{
  __shared__ float s_m[JC];
  __shared__ float s_part[4][64];
  __shared__ float s_h[64];
  const int b = blockIdx.x, tid = threadIdx.x;
  for (int i = tid; i < JC; i += 256) s_m[i] = sum_src[(long)b*JC + i] * (1.0f/243.0f);
  __syncthreads();
  const int n = tid & 63, part = tid >> 6;
  float s = 0.0f;
  const int k0 = part * 544;
  for (int k = k0; k < k0 + 544; ++k) s = fmaf(s_m[k], cw1[(long)k*64 + n], s);
  s_part[part][n] = s;
  __syncthreads();
  if (tid < 64) s_h[tid] = gelu_exact(s_part[0][tid] + s_part[1][tid] +
                                      s_part[2][tid] + s_part[3][tid] + cb1[tid]);
  __syncthreads();
  if (tid < 8){
    float v = cb2[tid];
    #pragma unroll
    for (int k = 0; k < 64; ++k) v = fmaf(s_h[k], cw2[k*8 + tid], v);
    out_lg[b*8 + tid] = v;
  }
}

extern "C" void kernel_launch(void* const* d_in, const int* in_sizes, int n_in,
                              void* d_out, int out_size, void* d_ws, size_t ws_size,
                              hipStream_t stream)
{
  const float* feat = (const float*)d_in[0];
  const float* pose = (const float*)d_in[1];
  const float* aw1  = (const float*)d_in[2];
  const float* ab1  = (const float*)d_in[3];
  const float* aw2  = (const float*)d_in[4];
  const float* ab2  = (const float*)d_in[5];
  const float* bw1  = (const float*)d_in[6];
  const float* bb1  = (const float*)d_in[7];
  const float* bw2  = (const float*)d_in[8];
  const float* bb2  = (const float*)d_in[9];
  const float* cw1  = (const float*)d_in[10];
  const float* cb1  = (const float*)d_in[11];
  const float* cw2  = (const float*)d_in[12];
  const float* cb2  = (const float*)d_in[13];

  float* out = (float*)d_out;
  float* out_pa  = out;                 // [NF,17,3]  793152
  float* out_aa  = out + 793152;        // [NF,17,1]  264384
  float* out_pbl = out + 1057536;       // [NF,15,1]  233280
  float* out_abl = out + 1290816;       // [NF,15,1]  233280
  float* out_lg  = out + 1524096;       // [64,8]     512

  float* mean_acc = (float*)d_ws;
  unsigned short* ws_wb = (unsigned short*)((char*)d_ws + WSO_WB);
  unsigned short* ws_wa = (unsigned short*)((char*)d_ws + WSO_WA);

  k_prep<<<dim3(20), dim3(256), 0, stream>>>(bw1, aw1, ws_wb, ws_wa);
  k_geom<<<dim3((NF + 255)/256), dim3(256), 0, stream>>>(pose, out_aa, out_abl,
                                                         out_pbl, mean_acc);
  k_fused<<<dim3(GRID_FUSED), dim3(320), 0, stream>>>(feat, ab1, aw2, ab2, bb1, bw2,
                                                      ws_wb, ws_wa,
                                                      out_pa, out_pbl, mean_acc);
  k_pblfix<<<dim3((NF*15 + 255)/256), dim3(256), 0, stream>>>(out_pbl, bb2);
  k_action<<<dim3(64), dim3(256), 0, stream>>>(mean_acc, cw1, cb1, cw2, cb2, out_lg);
}

// Round 10
// 247.813 us; speedup vs baseline: 1.3771x; 1.3771x over previous
//
#include <hip/hip_runtime.h>
#include <math.h>

#define NF 15552      // B*T
#define NJ 17
#define NC 128
#define JC 2176       // NJ*NC
#define TT 243        // frames per batch

constexpr int cA[15] = {0,1,2,0,4,5,0,7,8,0,10,11,0,13,14};
constexpr int cB[15] = {1,2,3,4,5,6,7,8,9,10,11,12,13,14,15};
constexpr int aJ[4] = {11,14,5,8};
constexpr int aP[4] = {10,13,4,7};
constexpr int aCc[4] = {12,15,6,9};

__device__ const int d_cA16[16] = {0,1,2,0,4,5,0,7,8,0,10,11,0,13,14,0};
__device__ const int d_cB16[16] = {1,2,3,4,5,6,7,8,9,10,11,12,13,14,15,0};

typedef __bf16 bf16x8 __attribute__((ext_vector_type(8)));
typedef float f32x4 __attribute__((ext_vector_type(4)));
typedef unsigned short u16x8 __attribute__((ext_vector_type(8)));

// ws layout (bytes):
//   [0)       mean_acc  64*JC f32   = 557056
//   [557056)  wb frags  65536
//   [622592)  wa frags  16384
//   [638976)  feat bf16 NF*JC*2     = 67682304   (only if ws_size permits)
#define WSO_WB  557056
#define WSO_WA  622592
#define WSO_F16 638976
#define WS_NEED (638976ull + (unsigned long long)NF*JC*2)

__device__ __forceinline__ float gelu_exact(float x){
  return 0.5f * x * (1.0f + erff(x * 0.7071067811865476f));
}
__device__ __forceinline__ float gelu_fast(float x){
  const float s2 = x * x;
  const float q  = fmaf(s2, -0.1029437f, -2.3021183f);
  const float e  = __builtin_amdgcn_exp2f(q * x);
  return x * __builtin_amdgcn_rcpf(1.0f + e);
}
__device__ __forceinline__ unsigned short bfc(float x){
  return __builtin_bit_cast(unsigned short, (__bf16)x);
}

// ---------------- prep: weights -> bf16 MFMA-fragment layout in ws ----------------
__global__ __launch_bounds__(256) void k_prep(const float* __restrict__ bw1,
                                              const float* __restrict__ aw1,
                                              unsigned short* __restrict__ ws_wb,
                                              unsigned short* __restrict__ ws_wa)
{
  const int u = blockIdx.x*256 + threadIdx.x;
  if (u < 4096){
    const int lane = u & 63, ks = (u>>6)&7, nf = (u>>9)&1, widx = u>>10;
    const int c = lane & 15, g = lane >> 4;
    const int col = widx*32 + nf*16 + c;
    u16x8 t;
    #pragma unroll
    for (int e = 0; e < 8; ++e) t[e] = bfc(bw1[(ks*32 + g*8 + e)*128 + col]);
    *(u16x8*)&ws_wb[u*8] = t;
  } else if (u < 4096 + 1024){
    const int v = u - 4096;
    const int lane = v & 63, nf = (v>>6)&3, kt = v>>8;
    const int c = lane & 15, g = lane >> 4;
    const int col = nf*16 + c;
    u16x8 t;
    #pragma unroll
    for (int e = 0; e < 8; ++e) t[e] = bfc(aw1[(kt*32 + g*8 + e)*64 + col]);
    *(u16x8*)&ws_wa[v*8] = t;
  }
}

// ---------------- geometry + mean_acc zeroing ----------------
__global__ __launch_bounds__(256) void k_geom(const float* __restrict__ pose,
                                              float* __restrict__ out_aa,
                                              float* __restrict__ out_abl,
                                              float* __restrict__ mean_acc)
{
  __shared__ float sp[256*51];
  const int tid = threadIdx.x;
  const int fbase = blockIdx.x * 256;
  const int nfr = min(256, NF - fbase);

  for (int u = tid; u < nfr*51; u += 256) sp[u] = pose[(long)fbase*51 + u];
  for (long i = (long)blockIdx.x*256 + tid; i < 64L*JC; i += (long)gridDim.x*256)
    mean_acc[i] = 0.0f;
  __syncthreads();

  if (tid < nfr){
    const int f = fbase + tid;
    const float* p = sp + tid*51;
    float px[NJ], py[NJ], pz[NJ];
    #pragma unroll
    for (int j = 0; j < NJ; ++j){ px[j] = p[3*j]; py[j] = p[3*j+1]; pz[j] = p[3*j+2]; }

    #pragma unroll
    for (int i = 0; i < 15; ++i){
      const int a = cA[i], b = cB[i];
      const float dx = px[b]-px[a], dy = py[b]-py[a], dz = pz[b]-pz[a];
      out_abl[(long)f*15 + i] = sqrtf(dx*dx + dy*dy + dz*dz);
    }

    float ang[NJ];
    #pragma unroll
    for (int j = 0; j < NJ; ++j) ang[j] = 0.0f;
    #pragma unroll
    for (int i = 0; i < 4; ++i){
      const int jj = aJ[i], pp = aP[i], cc = aCc[i];
      float v1x = px[jj]-px[pp], v1y = py[jj]-py[pp], v1z = pz[jj]-pz[pp];
      float v2x = px[cc]-px[jj], v2y = py[cc]-py[jj], v2z = pz[cc]-pz[jj];
      const float n1 = sqrtf(v1x*v1x + v1y*v1y + v1z*v1z) + 1e-10f;
      const float n2 = sqrtf(v2x*v2x + v2y*v2y + v2z*v2z) + 1e-10f;
      v1x /= n1; v1y /= n1; v1z /= n1;
      v2x /= n2; v2y /= n2; v2z /= n2;
      float d = v1x*v2x + v1y*v2y + v1z*v2z;
      d = fminf(fmaxf(d, -1.0f + 1e-7f), 1.0f - 1e-7f);
      ang[jj] = acosf(d);
    }
    #pragma unroll
    for (int j = 0; j < NJ; ++j) out_aa[(long)f*NJ + j] = ang[j];
  }
}

// ---------------- cvt: feat f32 -> bf16 (row-major) + fused mean ----------------
// 9 frames/block (batch-aligned: 243 = 27*9). grid = NF/9 = 1728. Pure streaming.
__global__ __launch_bounds__(256) void k_cvt(const float* __restrict__ feat,
                                             unsigned short* __restrict__ f16,
                                             float* __restrict__ mean_acc)
{
  const int tid = threadIdx.x;
  const long F0 = (long)blockIdx.x * 9;
  const int b = (int)(F0 / TT);
  const bool two = (tid < 16);      // 2176 elems = 272 u16x8 units; threads 0-15 take 2
  float m[8], m2[8];
  #pragma unroll
  for (int e = 0; e < 8; ++e){ m[e] = 0.f; m2[e] = 0.f; }

  for (int f = 0; f < 9; ++f){
    const float* src = feat + (F0 + f)*JC;
    unsigned short* dst = f16 + (F0 + f)*JC;
    {
      const float4 v0 = *(const float4*)(src + tid*8);
      const float4 v1 = *(const float4*)(src + tid*8 + 4);
      m[0]+=v0.x; m[1]+=v0.y; m[2]+=v0.z; m[3]+=v0.w;
      m[4]+=v1.x; m[5]+=v1.y; m[6]+=v1.z; m[7]+=v1.w;
      u16x8 q;
      q[0]=bfc(v0.x); q[1]=bfc(v0.y); q[2]=bfc(v0.z); q[3]=bfc(v0.w);
      q[4]=bfc(v1.x); q[5]=bfc(v1.y); q[6]=bfc(v1.z); q[7]=bfc(v1.w);
      *(u16x8*)&dst[tid*8] = q;
    }
    if (two){
      const int u = 256 + tid;
      const float4 v0 = *(const float4*)(src + u*8);
      const float4 v1 = *(const float4*)(src + u*8 + 4);
      m2[0]+=v0.x; m2[1]+=v0.y; m2[2]+=v0.z; m2[3]+=v0.w;
      m2[4]+=v1.x; m2[5]+=v1.y; m2[6]+=v1.z; m2[7]+=v1.w;
      u16x8 q;
      q[0]=bfc(v0.x); q[1]=bfc(v0.y); q[2]=bfc(v0.z); q[3]=bfc(v0.w);
      q[4]=bfc(v1.x); q[5]=bfc(v1.y); q[6]=bfc(v1.z); q[7]=bfc(v1.w);
      *(u16x8*)&dst[u*8] = q;
    }
  }
  #pragma unroll
  for (int e = 0; e < 8; ++e)
    atomicAdd(&mean_acc[(long)b*JC + tid*8 + e], m[e]);
  if (two){
    #pragma unroll
    for (int e = 0; e < 8; ++e)
      atomicAdd(&mean_acc[(long)b*JC + (256 + tid)*8 + e], m2[e]);
  }
}

// ---------------- fallback mean (f32 path): per-batch channel sums ----------------
__global__ __launch_bounds__(256) void k_mean(const float* __restrict__ feat,
                                              float* __restrict__ mean_acc)
{
  const int jc = blockIdx.x*256 + threadIdx.x;
  const int b = blockIdx.y;
  if (jc >= JC) return;
  float s = 0.0f;
  const float* p = feat + (long)b*TT*JC + jc;
  #pragma unroll 9
  for (int t = 0; t < TT; ++t) s += p[(long)t*JC];
  mean_acc[(long)b*JC + jc] = s;    // sum; k_action divides by 243
}

// ---------------- angle MLP: wave-autonomous, zero LDS, zero barriers ----------------
// Flat rows R = NF*17 = 264384. Wave: 3 tiles of 16 consecutive rows. Block: 4 waves.
// grid = 264384 / 192 = 1377.
template<int BF>
__global__ __launch_bounds__(256) void k_angle(const void* __restrict__ srcv,
    const unsigned short* __restrict__ ws_wa,
    const float* __restrict__ ab1, const float* __restrict__ aw2,
    const float* __restrict__ ab2, float* __restrict__ out_pa)
{
  const int tid = threadIdx.x, w = tid >> 6, lane = tid & 63;
  const int g = lane >> 4, c = lane & 15;

  bf16x8 wa[4][4];
  #pragma unroll
  for (int kt = 0; kt < 4; ++kt)
    #pragma unroll
    for (int nf = 0; nf < 4; ++nf)
      wa[kt][nf] = __builtin_bit_cast(bf16x8, *(const u16x8*)&ws_wa[((kt*4 + nf)*64 + lane)*8]);

  float ab1c[4], aw2c[4][3];
  #pragma unroll
  for (int nf = 0; nf < 4; ++nf){
    const int col = nf*16 + c;
    ab1c[nf] = ab1[col];
    #pragma unroll
    for (int m = 0; m < 3; ++m) aw2c[nf][m] = aw2[col*3 + m];
  }
  const float ab2c[3] = {ab2[0], ab2[1], ab2[2]};

  const long rbase = (long)blockIdx.x*192 + w*48;
  #pragma unroll
  for (int i = 0; i < 3; ++i){
    const long r0 = rbase + i*16;
    f32x4 acc[4];
    #pragma unroll
    for (int nf = 0; nf < 4; ++nf) acc[nf] = (f32x4)0.0f;

    #pragma unroll
    for (int kt = 0; kt < 4; ++kt){
      bf16x8 av;
      if (BF){
        const unsigned short* sp = (const unsigned short*)srcv + (r0 + c)*NC + kt*32 + g*8;
        av = __builtin_bit_cast(bf16x8, *(const u16x8*)sp);
      } else {
        const float* sp = (const float*)srcv + (r0 + c)*NC + kt*32 + g*8;
        const float4 a0 = *(const float4*)sp;
        const float4 a1 = *(const float4*)(sp + 4);
        u16x8 t;
        t[0]=bfc(a0.x); t[1]=bfc(a0.y); t[2]=bfc(a0.z); t[3]=bfc(a0.w);
        t[4]=bfc(a1.x); t[5]=bfc(a1.y); t[6]=bfc(a1.z); t[7]=bfc(a1.w);
        av = __builtin_bit_cast(bf16x8, t);
      }
      #pragma unroll
      for (int nf = 0; nf < 4; ++nf)
        acc[nf] = __builtin_amdgcn_mfma_f32_16x16x32_bf16(av, wa[kt][nf], acc[nf], 0, 0, 0);
    }

    float s[4][3];
    #pragma unroll
    for (int r = 0; r < 4; ++r){ s[r][0]=0.f; s[r][1]=0.f; s[r][2]=0.f; }
    #pragma unroll
    for (int nf = 0; nf < 4; ++nf)
      #pragma unroll
      for (int r = 0; r < 4; ++r){
        const float h = gelu_fast(acc[nf][r] + ab1c[nf]);
        s[r][0] = fmaf(h, aw2c[nf][0], s[r][0]);
        s[r][1] = fmaf(h, aw2c[nf][1], s[r][1]);
        s[r][2] = fmaf(h, aw2c[nf][2], s[r][2]);
      }
    #pragma unroll
    for (int r = 0; r < 4; ++r)
      #pragma unroll
      for (int m = 0; m < 3; ++m){
        float v = s[r][m];
        v += __shfl_xor(v, 1);
        v += __shfl_xor(v, 2);
        v += __shfl_xor(v, 4);
        v += __shfl_xor(v, 8);
        s[r][m] = v;
      }
    if (c == 0){
      #pragma unroll
      for (int r = 0; r < 4; ++r){
        const long row = r0 + g*4 + r;
        #pragma unroll
        for (int m = 0; m < 3; ++m)
          out_pa[row*3 + m] = s[r][m] + ab2c[m];
      }
    }
  }
}

// ---------------- bone MLP: one wave = one frame, full in-wave reduction ----------------
// 4 N-passes of 32 cols; wb frags from L2-hot ws. No LDS, no barriers, no atomics.
// Block: 4 waves x 3 frames = 12 frames. grid = NF/12 = 1296.
template<int BF>
__global__ __launch_bounds__(256) void k_bone(const void* __restrict__ srcv,
    const unsigned short* __restrict__ ws_wb,
    const float* __restrict__ bb1, const float* __restrict__ bw2,
    const float* __restrict__ bb2, float* __restrict__ out_pbl)
{
  const int tid = threadIdx.x, w = tid >> 6, lane = tid & 63;
  const int g = lane >> 4, c = lane & 15;

  float bb1c[8], bw2c[8];
  #pragma unroll
  for (int P = 0; P < 8; ++P){ bb1c[P] = bb1[P*16 + c]; bw2c[P] = bw2[P*16 + c]; }
  const float bb2c = bb2[0];
  const int jAo = d_cA16[c]*NC, jBo = d_cB16[c]*NC;

  #pragma unroll
  for (int i = 0; i < 3; ++i){
    const long frame = (long)blockIdx.x*12 + w*3 + i;

    bf16x8 af[8];
    if (BF){
      const unsigned short* fb = (const unsigned short*)srcv + frame*JC;
      #pragma unroll
      for (int ks = 0; ks < 8; ++ks)
        af[ks] = __builtin_bit_cast(bf16x8,
            *(const u16x8*)&fb[(ks < 4 ? jAo : jBo) + (ks & 3)*32 + g*8]);
    } else {
      const float* fb = (const float*)srcv + frame*JC;
      #pragma unroll
      for (int ks = 0; ks < 8; ++ks){
        const float* pa = fb + (ks < 4 ? jAo : jBo) + (ks & 3)*32 + g*8;
        const float4 a0 = *(const float4*)pa;
        const float4 a1 = *(const float4*)(pa + 4);
        u16x8 t;
        t[0]=bfc(a0.x); t[1]=bfc(a0.y); t[2]=bfc(a0.z); t[3]=bfc(a0.w);
        t[4]=bfc(a1.x); t[5]=bfc(a1.y); t[6]=bfc(a1.z); t[7]=bfc(a1.w);
        af[ks] = __builtin_bit_cast(bf16x8, t);
      }
    }

    float s[4] = {0.f, 0.f, 0.f, 0.f};
    #pragma unroll
    for (int nfp = 0; nfp < 4; ++nfp){
      f32x4 acc0 = (f32x4)0.0f, acc1 = (f32x4)0.0f;
      #pragma unroll
      for (int ks = 0; ks < 8; ++ks){
        const bf16x8 wb0 = __builtin_bit_cast(bf16x8,
            *(const u16x8*)&ws_wb[(((nfp*2 + 0)*8 + ks)*64 + lane)*8]);
        const bf16x8 wb1 = __builtin_bit_cast(bf16x8,
            *(const u16x8*)&ws_wb[(((nfp*2 + 1)*8 + ks)*64 + lane)*8]);
        acc0 = __builtin_amdgcn_mfma_f32_16x16x32_bf16(af[ks], wb0, acc0, 0, 0, 0);
        acc1 = __builtin_amdgcn_mfma_f32_16x16x32_bf16(af[ks], wb1, acc1, 0, 0, 0);
      }
      #pragma unroll
      for (int r = 0; r < 4; ++r)
        s[r] += gelu_fast(acc0[r] + bb1c[nfp*2    ]) * bw2c[nfp*2    ]
              + gelu_fast(acc1[r] + bb1c[nfp*2 + 1]) * bw2c[nfp*2 + 1];
    }
    #pragma unroll
    for (int r = 0; r < 4; ++r){
      s[r] += __shfl_xor(s[r], 1);
      s[r] += __shfl_xor(s[r], 2);
      s[r] += __shfl_xor(s[r], 4);
      s[r] += __shfl_xor(s[r], 8);
    }
    if (c == 0){
      #pragma unroll
      for (int r = 0; r < 4; ++r){
        const int bone = g*4 + r;
        if (bone < 15)
          out_pbl[frame*15 + bone] = fmaxf(s[r] + bb2c, 0.0f);
      }
    }
  }
}

// ---------------- action classifier (reads per-batch sums) ----------------
__global__ __launch_bounds__(256) void k_action(const float* __restrict__ sum_src,
    const float* __restrict__ cw1, const float* __restrict__ cb1,
    const float* __restrict__ cw2, const float* __restrict__ cb2,
    float* __restrict__ out_lg)
{
  __shared__ float s_m[JC];
  __shared__ float s_part[4][64];
  __shared__ float s_h[64];
  const int b = blockIdx.x, tid = threadIdx.x;
  for (int i = tid; i < JC; i += 256) s_m[i] = sum_src[(long)b*JC + i] * (1.0f/243.0f);
  __syncthreads();
  const int n = tid & 63, part = tid >> 6;
  float s = 0.0f;
  const int k0 = part * 544;
  for (int k = k0; k < k0 + 544; ++k) s = fmaf(s_m[k], cw1[(long)k*64 + n], s);
  s_part[part][n] = s;
  __syncthreads();
  if (tid < 64) s_h[tid] = gelu_exact(s_part[0][tid] + s_part[1][tid] +
                                      s_part[2][tid] + s_part[3][tid] + cb1[tid]);
  __syncthreads();
  if (tid < 8){
    float v = cb2[tid];
    #pragma unroll
    for (int k = 0; k < 64; ++k) v = fmaf(s_h[k], cw2[k*8 + tid], v);
    out_lg[b*8 + tid] = v;
  }
}

extern "C" void kernel_launch(void* const* d_in, const int* in_sizes, int n_in,
                              void* d_out, int out_size, void* d_ws, size_t ws_size,
                              hipStream_t stream)
{
  const float* feat = (const float*)d_in[0];
  const float* pose = (const float*)d_in[1];
  const float* aw1  = (const float*)d_in[2];
  const float* ab1  = (const float*)d_in[3];
  const float* aw2  = (const float*)d_in[4];
  const float* ab2  = (const float*)d_in[5];
  const float* bw1  = (const float*)d_in[6];
  const float* bb1  = (const float*)d_in[7];
  const float* bw2  = (const float*)d_in[8];
  const float* bb2  = (const float*)d_in[9];
  const float* cw1  = (const float*)d_in[10];
  const float* cb1  = (const float*)d_in[11];
  const float* cw2  = (const float*)d_in[12];
  const float* cb2  = (const float*)d_in[13];

  float* out = (float*)d_out;
  float* out_pa  = out;                 // [NF,17,3]  793152
  float* out_aa  = out + 793152;        // [NF,17,1]  264384
  float* out_pbl = out + 1057536;       // [NF,15,1]  233280
  float* out_abl = out + 1290816;       // [NF,15,1]  233280
  float* out_lg  = out + 1524096;       // [64,8]     512

  float* mean_acc = (float*)d_ws;
  unsigned short* ws_wb  = (unsigned short*)((char*)d_ws + WSO_WB);
  unsigned short* ws_wa  = (unsigned short*)((char*)d_ws + WSO_WA);
  unsigned short* ws_f16 = (unsigned short*)((char*)d_ws + WSO_F16);

  const bool useBF = (ws_size >= WS_NEED);

  k_prep<<<dim3(20), dim3(256), 0, stream>>>(bw1, aw1, ws_wb, ws_wa);
  k_geom<<<dim3((NF + 255)/256), dim3(256), 0, stream>>>(pose, out_aa, out_abl, mean_acc);

  if (useBF){
    k_cvt<<<dim3(NF/9), dim3(256), 0, stream>>>(feat, ws_f16, mean_acc);
    k_angle<1><<<dim3((NF*NJ)/192), dim3(256), 0, stream>>>(ws_f16, ws_wa, ab1, aw2, ab2, out_pa);
    k_bone<1><<<dim3(NF/12), dim3(256), 0, stream>>>(ws_f16, ws_wb, bb1, bw2, bb2, out_pbl);
  } else {
    k_mean<<<dim3((JC + 255)/256, 64), dim3(256), 0, stream>>>(feat, mean_acc);
    k_angle<0><<<dim3((NF*NJ)/192), dim3(256), 0, stream>>>(feat, ws_wa, ab1, aw2, ab2, out_pa);
    k_bone<0><<<dim3(NF/12), dim3(256), 0, stream>>>(feat, ws_wb, bb1, bw2, bb2, out_pbl);
  }

  k_action<<<dim3(64), dim3(256), 0, stream>>>(mean_acc, cw1, cb1, cw2, cb2, out_lg);
}